// Round 4
// baseline (256.286 us; speedup 1.0000x reference)
//
#include <hip/hip_runtime.h>

#define DD 256
#define BB 8
#define NA 360

typedef _Float16 half2_t __attribute__((ext_vector_type(2)));

#if defined(__has_builtin)
#if __has_builtin(__builtin_elementwise_fma)
#define PKFMA(a, b, c) __builtin_elementwise_fma((a), (b), (c))
#endif
#endif
#ifndef PKFMA
#define PKFMA(a, b, c) ((a) * (b) + (c))
#endif

__device__ __forceinline__ half2_t h2(unsigned u) {
    return __builtin_bit_cast(half2_t, u);
}
__device__ __forceinline__ half2_t bcast2(float w) {   // v_cvt_pkrtz (w,w)
    return __builtin_bit_cast(half2_t, __builtin_amdgcn_cvt_pkrtz(w, w));
}
__device__ __forceinline__ unsigned pk_f16(float a, float b) {
    unsigned short ua = __builtin_bit_cast(unsigned short, (_Float16)a);
    unsigned short ub = __builtin_bit_cast(unsigned short, (_Float16)b);
    return (unsigned)ua | ((unsigned)ub << 16);
}
__device__ __forceinline__ uint4 sel4(bool c, uint4 a, uint4 b) {
    uint4 r;
    r.x = c ? a.x : b.x; r.y = c ? a.y : b.y;
    r.z = c ? a.z : b.z; r.w = c ? a.w : b.w;
    return r;
}

// ---- pack: (B,1,D,D) fp32 -> f16x8/pixel pN + transposed pT ---------------
__global__ __launch_bounds__(256) void pack_f16(const float* __restrict__ x,
                                                uint4* __restrict__ pN,
                                                uint4* __restrict__ pT) {
    __shared__ uint4 t[16][17];
    const int tx = threadIdx.x & 15;
    const int ty = threadIdx.x >> 4;
    const int x0 = (blockIdx.x & 15) * 16;
    const int y0 = (blockIdx.x >> 4) * 16;

    const int pix = (y0 + ty) * DD + x0 + tx;
    uint4 v;
    v.x = pk_f16(x[0 * DD * DD + pix], x[1 * DD * DD + pix]);
    v.y = pk_f16(x[2 * DD * DD + pix], x[3 * DD * DD + pix]);
    v.z = pk_f16(x[4 * DD * DD + pix], x[5 * DD * DD + pix]);
    v.w = pk_f16(x[6 * DD * DD + pix], x[7 * DD * DD + pix]);
    pN[pix] = v;
    t[ty][tx] = v;
    __syncthreads();
    pT[(x0 + ty) * DD + y0 + tx] = t[tx][ty];
}

// ===========================================================================
// DIAGNOSTIC ROUND (R15 = R14 resubmit + extra probe). Order on stream:
//   radon_roll (probe)  ->  radon_noroll_pred (probe)  ->  radon_pk (OUTPUT)
// Probes' outputs are fully overwritten by radon_pk, so the round passes with
// R10 numerics while rocprof rows give each probe's true duration.
// Models under test (per-step gather cost): per-active-lane vs per-instr vs
// footprint. Decision rule in journal (pre-committed).
// ===========================================================================

// ---- probe A: rolling-quad (term-set bug unlocated; timing only) ----------
struct Stream {
    float uh;
    int xp, yp;
    uint4 q00, q10, q01, q11;   // corner quad: rows {yp,yp+1} x cols {xp,xp+1}
};

__device__ __forceinline__ void fma8(half2_t acc[4], const uint4& q, half2_t w) {
    acc[0] = PKFMA(h2(q.x), w, acc[0]);
    acc[1] = PKFMA(h2(q.y), w, acc[1]);
    acc[2] = PKFMA(h2(q.z), w, acc[2]);
    acc[3] = PKFMA(h2(q.w), w, acc[3]);
}

__device__ __forceinline__ void flushF(half2_t acc2[4], float accF[BB]) {
#pragma unroll
    for (int j = 0; j < 4; ++j) {
        accF[2 * j]     += (float)acc2[j].x;
        accF[2 * j + 1] += (float)acc2[j].y;
        acc2[j] = half2_t{(_Float16)0, (_Float16)0};
    }
}

template<int SX, bool INIT>
__device__ __forceinline__ void step(const uint4* __restrict__ P,
                                     float dx, float dy, float ax, float ay,
                                     Stream& S, half2_t acc[4]) {
    const float ix = fmaf(dx, S.uh, ax);
    const float iy = fmaf(dy, S.uh, ay);
    const float x0f = floorf(ix), y0f = floorf(iy);
    const int x0 = (int)x0f, y0 = (int)y0f;
    const float wx1 = ix - x0f, wy1 = iy - y0f;
    const float wx0 = 1.f - wx1, wy0 = 1.f - wy1;
    const bool vxl = ((unsigned)x0 < 256u);
    const bool vxh = ((unsigned)(x0 + 1) < 256u);
    const bool vyl = ((unsigned)y0 < 256u);
    const bool vyh = ((unsigned)(y0 + 1) < 256u);
    const int base = y0 * DD + x0;

    if (INIT) {
        const uint4 z = uint4{0u, 0u, 0u, 0u};
        S.q00 = z; S.q10 = z; S.q01 = z; S.q11 = z;
        if (vxl && vyl) S.q00 = P[base];
        if (vxh && vyl) S.q10 = P[base + 1];
        if (vxl && vyh) S.q01 = P[base + 256];
        if (vxh && vyh) S.q11 = P[base + 257];
    } else {
        const bool cs = (x0 != S.xp);
        const bool rs = (y0 != S.yp);
        if (SX > 0) {
            const uint4 u  = sel4(rs, S.q11, S.q10);
            const uint4 v  = sel4(rs, S.q01, S.q00);
            const uint4 w2 = sel4(cs, S.q11, S.q01);
            S.q00 = sel4(cs, u, v);
            S.q10 = u;
            S.q01 = w2;
            if (cs && vxh && vyl) S.q10 = P[base + 1];
            if (rs && vxl && vyh) S.q01 = P[base + 256];
            if ((cs || rs) && vxh && vyh) S.q11 = P[base + 257];
        } else {
            const uint4 v  = sel4(rs, S.q01, S.q00);
            const uint4 u  = sel4(rs, S.q11, S.q10);
            const uint4 w2 = sel4(cs, S.q01, S.q11);
            S.q10 = sel4(cs, v, u);
            S.q00 = v;
            S.q11 = w2;
            if (cs && vxl && vyl) S.q00 = P[base];
            if (rs && vxh && vyh) S.q11 = P[base + 257];
            if ((cs || rs) && vxl && vyh) S.q01 = P[base + 256];
        }
    }
    S.xp = x0; S.yp = y0;

    const float vx0 = vxl ? wx0 : 0.f;
    const float vx1 = vxh ? wx1 : 0.f;
    const float vy0 = vyl ? wy0 : 0.f;
    const float vy1 = vyh ? wy1 : 0.f;
    fma8(acc, S.q00, bcast2(vx0 * vy0));
    fma8(acc, S.q10, bcast2(vx1 * vy0));
    fma8(acc, S.q01, bcast2(vx0 * vy1));
    fma8(acc, S.q11, bcast2(vx1 * vy1));
}

template<int SX>
__device__ __forceinline__ void run_quarter(const uint4* __restrict__ P,
                                            float dx, float dy, float ax, float ay,
                                            float dir, int h0, float accF[BB]) {
    half2_t acc2[4];
#pragma unroll
    for (int j = 0; j < 4; ++j) acc2[j] = half2_t{(_Float16)0, (_Float16)0};

    Stream S0, S1;
    S0.uh = (float)(dir > 0.f ? h0      : h0 + 31) - 127.5f;
    S1.uh = (float)(dir > 0.f ? h0 + 32 : h0 + 63) - 127.5f;
    step<SX, true>(P, dx, dy, ax, ay, S0, acc2);
    step<SX, true>(P, dx, dy, ax, ay, S1, acc2);
    S0.uh += dir; step<SX, false>(P, dx, dy, ax, ay, S0, acc2);
    S1.uh += dir; step<SX, false>(P, dx, dy, ax, ay, S1, acc2);
    flushF(acc2, accF);
    for (int seg = 1; seg < 16; ++seg) {
        S0.uh += dir; step<SX, false>(P, dx, dy, ax, ay, S0, acc2);
        S1.uh += dir; step<SX, false>(P, dx, dy, ax, ay, S1, acc2);
        S0.uh += dir; step<SX, false>(P, dx, dy, ax, ay, S0, acc2);
        S1.uh += dir; step<SX, false>(P, dx, dy, ax, ay, S1, acc2);
        flushF(acc2, accF);
    }
}

__global__ __launch_bounds__(256) void radon_roll(const uint4* __restrict__ pN,
                                                  const uint4* __restrict__ pT,
                                                  float* __restrict__ out) {
    const int a    = blockIdx.x;
    const int wseg = blockIdx.y;
    const int g    = threadIdx.x >> 6;
    const int lane = threadIdx.x & 63;
    const int w    = wseg * 64 + lane;

    const float ang = (float)a * 0.5f;
    const float t = ang * 0.017453292519943295f;
    const float s = sinf(t);
    const float c = cosf(t);

    const float uw  = (float)w - 127.5f;
    const float axN = fmaf(c, uw, 127.5f);
    const float ayN = fmaf(s, uw, 127.5f);

    const uint4* __restrict__ P;
    float ax, dx, ay, dy;
    if (fabsf(s) <= fabsf(c)) { P = pN; ax = axN; dx = -s; ay = ayN; dy = c;  }
    else                      { P = pT; ax = ayN; dx = c;  ay = axN; dy = -s; }

    const float dir = (dy >= 0.f) ? 1.f : -1.f;
    const float dxe = dx * dir;
    const int h0 = 64 * g;

    float accF[BB];
#pragma unroll
    for (int b = 0; b < BB; ++b) accF[b] = 0.f;

    if (dxe >= 0.f) run_quarter<+1>(P, dx, dy, ax, ay, dir, h0, accF);
    else            run_quarter<-1>(P, dx, dy, ax, ay, dir, h0, accF);

    __shared__ float part[4][64][BB];
#pragma unroll
    for (int b = 0; b < BB; b += 4)
        *(float4*)&part[g][lane][b] = make_float4(accF[b], accF[b + 1], accF[b + 2], accF[b + 3]);
    __syncthreads();

    const float sc = 1.0f / 256.0f;
#pragma unroll
    for (int k = 0; k < 2; ++k) {
        const int id = threadIdx.x + k * 256;
        const int b  = id >> 6;
        const int wl = id & 63;
        const float v = part[0][wl][b] + part[1][wl][b] + part[2][wl][b] + part[3][wl][b];
        out[(size_t)b * NA * DD + (size_t)a * DD + wseg * 64 + wl] = v * sc;
    }
}

// ---- probe B: R10 traversal, 4 exec-predicated loads (bit-exact vs R10) ---
__global__ __launch_bounds__(256) void radon_noroll_pred(const uint4* __restrict__ pN,
                                                         const uint4* __restrict__ pT,
                                                         float* __restrict__ out) {
    const int a    = blockIdx.x;
    const int wseg = blockIdx.y;
    const int g    = threadIdx.x >> 6;
    const int lane = threadIdx.x & 63;
    const int w    = wseg * 64 + lane;

    const float ang = (float)a * 0.5f;
    const float t = ang * 0.017453292519943295f;
    const float s = sinf(t);
    const float c = cosf(t);

    const float uw  = (float)w - 127.5f;
    const float axN = fmaf(c, uw, 127.5f);
    const float ayN = fmaf(s, uw, 127.5f);

    const uint4* __restrict__ P;
    float ax, dx, ay, dy;
    if (fabsf(s) <= fabsf(c)) { P = pN; ax = axN; dx = -s; ay = ayN; dy = c;  }
    else                      { P = pT; ax = ayN; dx = c;  ay = axN; dy = -s; }

    half2_t acc2[4];
#pragma unroll
    for (int j = 0; j < 4; ++j) acc2[j] = half2_t{(_Float16)0, (_Float16)0};

#pragma unroll 4
    for (int i = 0; i < 64; ++i) {
        const float uh = (float)(g + 4 * i) - 127.5f;
        const float ix = fmaf(dx, uh, ax);
        const float iy = fmaf(dy, uh, ay);
        const float x0f = floorf(ix), y0f = floorf(iy);
        const float wx1 = ix - x0f, wy1 = iy - y0f;
        const float wx0 = 1.f - wx1, wy0 = 1.f - wy1;
        const int x0 = (int)x0f, y0 = (int)y0f;
        const bool vxl = ((unsigned)x0 < 256u);
        const bool vxh = ((unsigned)(x0 + 1) < 256u);
        const bool vyl = ((unsigned)y0 < 256u);
        const bool vyh = ((unsigned)(y0 + 1) < 256u);
        const float vx0 = vxl ? wx0 : 0.f;
        const float vx1 = vxh ? wx1 : 0.f;
        const float vy0 = vyl ? wy0 : 0.f;
        const float vy1 = vyh ? wy1 : 0.f;
        const int base = y0 * DD + x0;

        const uint4 z = uint4{0u, 0u, 0u, 0u};
        uint4 q00 = z, q10 = z, q01 = z, q11 = z;
        if (vxl && vyl) q00 = P[base];
        if (vxh && vyl) q10 = P[base + 1];
        if (vxl && vyh) q01 = P[base + 256];
        if (vxh && vyh) q11 = P[base + 257];

        const half2_t w00 = bcast2(vx0 * vy0);
        const half2_t w10 = bcast2(vx1 * vy0);
        const half2_t w01 = bcast2(vx0 * vy1);
        const half2_t w11 = bcast2(vx1 * vy1);

        fma8(acc2, q00, w00);
        fma8(acc2, q10, w10);
        fma8(acc2, q01, w01);
        fma8(acc2, q11, w11);
    }

    float acc[BB];
#pragma unroll
    for (int j = 0; j < 4; ++j) {
        acc[2 * j]     = (float)acc2[j].x;
        acc[2 * j + 1] = (float)acc2[j].y;
    }

    __shared__ float part[4][64][BB];
#pragma unroll
    for (int b = 0; b < BB; b += 4)
        *(float4*)&part[g][lane][b] = make_float4(acc[b], acc[b + 1], acc[b + 2], acc[b + 3]);
    __syncthreads();

    const float sc = 1.0f / 256.0f;
#pragma unroll
    for (int k = 0; k < 2; ++k) {
        const int id = threadIdx.x + k * 256;
        const int b  = id >> 6;
        const int wl = id & 63;
        const float v = part[0][wl][b] + part[1][wl][b] + part[2][wl][b] + part[3][wl][b];
        out[(size_t)b * NA * DD + (size_t)a * DD + wseg * 64 + wl] = v * sc;
    }
}

// ---- radon (verbatim R10 known-good: produces the final output) -----------
__global__ __launch_bounds__(256) void radon_pk(const uint4* __restrict__ pN,
                                                const uint4* __restrict__ pT,
                                                float* __restrict__ out) {
    const int a    = blockIdx.x;            // angle
    const int wseg = blockIdx.y;            // 0..3
    const int g    = threadIdx.x >> 6;      // wave = h-phase 0..3
    const int lane = threadIdx.x & 63;
    const int w    = wseg * 64 + lane;

    const float ang = (float)a * 0.5f;
    const float t = ang * 0.017453292519943295f;
    const float s = sinf(t);
    const float c = cosf(t);

    const float uw  = (float)w - 127.5f;
    const float axN = fmaf(c, uw, 127.5f);
    const float ayN = fmaf(s, uw, 127.5f);

    const uint4* __restrict__ P;
    float ax, dx, ay, dy;                    // inner = ax+dx*uh, row = ay+dy*uh
    if (fabsf(s) <= fabsf(c)) { P = pN; ax = axN; dx = -s; ay = ayN; dy = c;  }
    else                      { P = pT; ax = ayN; dx = c;  ay = axN; dy = -s; }

    half2_t acc2[4];
#pragma unroll
    for (int j = 0; j < 4; ++j) acc2[j] = half2_t{(_Float16)0, (_Float16)0};

#pragma unroll 4
    for (int i = 0; i < 64; ++i) {
        const float uh = (float)(g + 4 * i) - 127.5f;
        const float ix = fmaf(dx, uh, ax);
        const float iy = fmaf(dy, uh, ay);
        const float x0f = floorf(ix), y0f = floorf(iy);
        const float wx1 = ix - x0f, wy1 = iy - y0f;
        const float wx0 = 1.f - wx1, wy0 = 1.f - wy1;
        const int x0 = (int)x0f, y0 = (int)y0f;
        const float vx0 = ((unsigned)x0 < 256u) ? wx0 : 0.f;
        const float vx1 = ((unsigned)(x0 + 1) < 256u) ? wx1 : 0.f;
        const float vy0 = ((unsigned)y0 < 256u) ? wy0 : 0.f;
        const float vy1 = ((unsigned)(y0 + 1) < 256u) ? wy1 : 0.f;
        const int x0c = min(max(x0, 0), 255);
        const int x1c = min(max(x0 + 1, 0), 255);
        const int y0c = min(max(y0, 0), 255);
        const int y1c = min(max(y0 + 1, 0), 255);

        const uint4 q00 = P[y0c * DD + x0c];
        const uint4 q10 = P[y0c * DD + x1c];
        const uint4 q01 = P[y1c * DD + x0c];
        const uint4 q11 = P[y1c * DD + x1c];

        const half2_t w00 = bcast2(vx0 * vy0);
        const half2_t w10 = bcast2(vx1 * vy0);
        const half2_t w01 = bcast2(vx0 * vy1);
        const half2_t w11 = bcast2(vx1 * vy1);

        acc2[0] = PKFMA(h2(q00.x), w00, acc2[0]);
        acc2[1] = PKFMA(h2(q00.y), w00, acc2[1]);
        acc2[2] = PKFMA(h2(q00.z), w00, acc2[2]);
        acc2[3] = PKFMA(h2(q00.w), w00, acc2[3]);
        acc2[0] = PKFMA(h2(q10.x), w10, acc2[0]);
        acc2[1] = PKFMA(h2(q10.y), w10, acc2[1]);
        acc2[2] = PKFMA(h2(q10.z), w10, acc2[2]);
        acc2[3] = PKFMA(h2(q10.w), w10, acc2[3]);
        acc2[0] = PKFMA(h2(q01.x), w01, acc2[0]);
        acc2[1] = PKFMA(h2(q01.y), w01, acc2[1]);
        acc2[2] = PKFMA(h2(q01.z), w01, acc2[2]);
        acc2[3] = PKFMA(h2(q01.w), w01, acc2[3]);
        acc2[0] = PKFMA(h2(q11.x), w11, acc2[0]);
        acc2[1] = PKFMA(h2(q11.y), w11, acc2[1]);
        acc2[2] = PKFMA(h2(q11.z), w11, acc2[2]);
        acc2[3] = PKFMA(h2(q11.w), w11, acc2[3]);
    }

    float acc[BB];
#pragma unroll
    for (int j = 0; j < 4; ++j) {
        acc[2 * j]     = (float)acc2[j].x;
        acc[2 * j + 1] = (float)acc2[j].y;
    }

    __shared__ float part[4][64][BB];        // 8 KB
#pragma unroll
    for (int b = 0; b < BB; b += 4)
        *(float4*)&part[g][lane][b] = make_float4(acc[b], acc[b + 1], acc[b + 2], acc[b + 3]);
    __syncthreads();

    const float sc = 1.0f / 256.0f;
#pragma unroll
    for (int k = 0; k < 2; ++k) {
        const int id = threadIdx.x + k * 256;  // 0..511 -> (b, wl)
        const int b  = id >> 6;
        const int wl = id & 63;
        const float v = part[0][wl][b] + part[1][wl][b] + part[2][wl][b] + part[3][wl][b];
        out[(size_t)b * NA * DD + (size_t)a * DD + wseg * 64 + wl] = v * sc;
    }
}

// ---- fallback (ws too small): direct fp32 gather with atomics -------------
__global__ __launch_bounds__(256) void radon_direct(const float* __restrict__ x,
                                                    float* __restrict__ out) {
    const int a  = blockIdx.x;
    const int hc = blockIdx.y;
    const int w  = threadIdx.x;
    const float ang = (float)a * 0.5f;
    const float t = ang * 0.017453292519943295f;
    const float s = sinf(t);
    const float c = cosf(t);
    const float uw = (float)w - 127.5f;
    const float ax = fmaf(c, uw, 127.5f);
    const float ay = fmaf(s, uw, 127.5f);

    float acc[BB];
#pragma unroll
    for (int b = 0; b < BB; ++b) acc[b] = 0.f;

    const int h0 = hc * 32;
    for (int i = 0; i < 32; ++i) {
        const float uh = (float)(h0 + i) - 127.5f;
        const float ix = fmaf(-s, uh, ax);
        const float iy = fmaf(c, uh, ay);
        const float x0f = floorf(ix), y0f = floorf(iy);
        const float wx1 = ix - x0f, wy1 = iy - y0f;
        const float wx0 = 1.f - wx1, wy0 = 1.f - wy1;
        const int x0 = (int)x0f, y0 = (int)y0f;
        const float vx0 = ((unsigned)x0 < 256u) ? wx0 : 0.f;
        const float vx1 = ((unsigned)(x0 + 1) < 256u) ? wx1 : 0.f;
        const float vy0 = ((unsigned)y0 < 256u) ? wy0 : 0.f;
        const float vy1 = ((unsigned)(y0 + 1) < 256u) ? wy1 : 0.f;
        const int x0c = min(max(x0, 0), 255);
        const int x1c = min(max(x0 + 1, 0), 255);
        const int y0c = min(max(y0, 0), 255);
        const int y1c = min(max(y0 + 1, 0), 255);
        const float w00 = vx0 * vy0, w10 = vx1 * vy0;
        const float w01 = vx0 * vy1, w11 = vx1 * vy1;
        const int l00 = y0c * DD + x0c, l10 = y0c * DD + x1c;
        const int l01 = y1c * DD + x0c, l11 = y1c * DD + x1c;
#pragma unroll
        for (int b = 0; b < BB; ++b) {
            const float* ib = x + (size_t)b * DD * DD;
            acc[b] = fmaf(ib[l00], w00, acc[b]);
            acc[b] = fmaf(ib[l10], w10, acc[b]);
            acc[b] = fmaf(ib[l01], w01, acc[b]);
            acc[b] = fmaf(ib[l11], w11, acc[b]);
        }
    }

    const float sc = 1.0f / 256.0f;
    float* o = out + (size_t)a * DD + w;
#pragma unroll
    for (int b = 0; b < BB; ++b)
        atomicAdd(o + (size_t)b * NA * DD, acc[b] * sc);
}

extern "C" void kernel_launch(void* const* d_in, const int* in_sizes, int n_in,
                              void* d_out, int out_size, void* d_ws, size_t ws_size,
                              hipStream_t stream) {
    const float* x = (const float*)d_in[0];
    float* out = (float*)d_out;

    const size_t need = 2ull * DD * DD * sizeof(uint4);  // 2 MiB
    if (ws_size >= need) {
        uint4* pN = (uint4*)d_ws;
        uint4* pT = pN + (size_t)DD * DD;
        pack_f16<<<256, 256, 0, stream>>>(x, pN, pT);
        // probes: results fully overwritten by radon_pk below
        radon_roll<<<dim3(NA, 4), 256, 0, stream>>>(pN, pT, out);
        radon_noroll_pred<<<dim3(NA, 4), 256, 0, stream>>>(pN, pT, out);
        // known-good R10 kernel produces the final output
        radon_pk<<<dim3(NA, 4), 256, 0, stream>>>(pN, pT, out);
    } else {
        (void)hipMemsetAsync(d_out, 0, (size_t)out_size * sizeof(float), stream);
        radon_direct<<<dim3(NA, 8), 256, 0, stream>>>(x, out);
    }
}

// Round 5
// 125.810 us; speedup vs baseline: 2.0371x; 2.0371x over previous
//
#include <hip/hip_runtime.h>

#define DD 256
#define BB 8
#define NA 360

typedef _Float16 half2_t __attribute__((ext_vector_type(2)));

#if defined(__has_builtin)
#if __has_builtin(__builtin_elementwise_fma)
#define PKFMA(a, b, c) __builtin_elementwise_fma((a), (b), (c))
#endif
#endif
#ifndef PKFMA
#define PKFMA(a, b, c) ((a) * (b) + (c))
#endif

__device__ __forceinline__ half2_t h2(unsigned u) {
    return __builtin_bit_cast(half2_t, u);
}
__device__ __forceinline__ half2_t bcast2(float w) {   // v_cvt_pkrtz (w,w)
    return __builtin_bit_cast(half2_t, __builtin_amdgcn_cvt_pkrtz(w, w));
}
__device__ __forceinline__ unsigned pk_f16(float a, float b) {
    unsigned short ua = __builtin_bit_cast(unsigned short, (_Float16)a);
    unsigned short ub = __builtin_bit_cast(unsigned short, (_Float16)b);
    return (unsigned)ua | ((unsigned)ub << 16);
}

// ---- pack: (B,1,D,D) fp32 -> f16x8/pixel pN + transposed pT ---------------
__global__ __launch_bounds__(256) void pack_f16(const float* __restrict__ x,
                                                uint4* __restrict__ pN,
                                                uint4* __restrict__ pT) {
    __shared__ uint4 t[16][17];
    const int tx = threadIdx.x & 15;
    const int ty = threadIdx.x >> 4;
    const int x0 = (blockIdx.x & 15) * 16;
    const int y0 = (blockIdx.x >> 4) * 16;

    const int pix = (y0 + ty) * DD + x0 + tx;
    uint4 v;
    v.x = pk_f16(x[0 * DD * DD + pix], x[1 * DD * DD + pix]);
    v.y = pk_f16(x[2 * DD * DD + pix], x[3 * DD * DD + pix]);
    v.z = pk_f16(x[4 * DD * DD + pix], x[5 * DD * DD + pix]);
    v.w = pk_f16(x[6 * DD * DD + pix], x[7 * DD * DD + pix]);
    pN[pix] = v;
    t[ty][tx] = v;
    __syncthreads();
    pT[(x0 + ty) * DD + y0 + tx] = t[tx][ty];
}

// ---- radon, predicated-gather (R16 winner; bit-exact vs R10) --------------
// R4 diagnostic: rolling-quad = 81.6us (DEAD: VALU/occupancy cost > load
// savings); predicated variant inferred ~50us from wall-clock decomposition.
// vs R10: OOB corners are exec-masked (zero-fill) instead of clamp-loaded.
// Bit-exact: OOB corner in R10 contributes clamped_val*0.0 = +0 (f16 FMA);
// here 0*0 = +0. Also collapses addressing: all 4 corners derive from ONE
// base (base, +1, +256, +257) vs 4 independently clamped address calcs.
__global__ __launch_bounds__(256) void radon_pred(const uint4* __restrict__ pN,
                                                  const uint4* __restrict__ pT,
                                                  float* __restrict__ out) {
    const int a    = blockIdx.x;            // angle
    const int wseg = blockIdx.y;            // 0..3
    const int g    = threadIdx.x >> 6;      // wave = h-phase 0..3
    const int lane = threadIdx.x & 63;
    const int w    = wseg * 64 + lane;

    const float ang = (float)a * 0.5f;
    const float t = ang * 0.017453292519943295f;
    const float s = sinf(t);
    const float c = cosf(t);

    const float uw  = (float)w - 127.5f;
    const float axN = fmaf(c, uw, 127.5f);
    const float ayN = fmaf(s, uw, 127.5f);

    // inner coord = contiguous dim of chosen layout (h-step = min(|s|,|c|))
    const uint4* __restrict__ P;
    float ax, dx, ay, dy;                    // inner = ax+dx*uh, row = ay+dy*uh
    if (fabsf(s) <= fabsf(c)) { P = pN; ax = axN; dx = -s; ay = ayN; dy = c;  }
    else                      { P = pT; ax = ayN; dx = c;  ay = axN; dy = -s; }

    half2_t acc2[4];
#pragma unroll
    for (int j = 0; j < 4; ++j) acc2[j] = half2_t{(_Float16)0, (_Float16)0};

    // h = g + 4*i : the block's 4 waves march through adjacent h together
#pragma unroll 4
    for (int i = 0; i < 64; ++i) {
        const float uh = (float)(g + 4 * i) - 127.5f;
        const float ix = fmaf(dx, uh, ax);
        const float iy = fmaf(dy, uh, ay);
        const float x0f = floorf(ix), y0f = floorf(iy);
        const float wx1 = ix - x0f, wy1 = iy - y0f;
        const float wx0 = 1.f - wx1, wy0 = 1.f - wy1;
        const int x0 = (int)x0f, y0 = (int)y0f;
        const bool vxl = ((unsigned)x0 < 256u);
        const bool vxh = ((unsigned)(x0 + 1) < 256u);
        const bool vyl = ((unsigned)y0 < 256u);
        const bool vyh = ((unsigned)(y0 + 1) < 256u);
        const float vx0 = vxl ? wx0 : 0.f;
        const float vx1 = vxh ? wx1 : 0.f;
        const float vy0 = vyl ? wy0 : 0.f;
        const float vy1 = vyh ? wy1 : 0.f;
        const int base = y0 * DD + x0;

        const uint4 z = uint4{0u, 0u, 0u, 0u};
        uint4 q00 = z, q10 = z, q01 = z, q11 = z;
        if (vxl && vyl) q00 = P[base];
        if (vxh && vyl) q10 = P[base + 1];
        if (vxl && vyh) q01 = P[base + 256];
        if (vxh && vyh) q11 = P[base + 257];

        const half2_t w00 = bcast2(vx0 * vy0);
        const half2_t w10 = bcast2(vx1 * vy0);
        const half2_t w01 = bcast2(vx0 * vy1);
        const half2_t w11 = bcast2(vx1 * vy1);

        acc2[0] = PKFMA(h2(q00.x), w00, acc2[0]);
        acc2[1] = PKFMA(h2(q00.y), w00, acc2[1]);
        acc2[2] = PKFMA(h2(q00.z), w00, acc2[2]);
        acc2[3] = PKFMA(h2(q00.w), w00, acc2[3]);
        acc2[0] = PKFMA(h2(q10.x), w10, acc2[0]);
        acc2[1] = PKFMA(h2(q10.y), w10, acc2[1]);
        acc2[2] = PKFMA(h2(q10.z), w10, acc2[2]);
        acc2[3] = PKFMA(h2(q10.w), w10, acc2[3]);
        acc2[0] = PKFMA(h2(q01.x), w01, acc2[0]);
        acc2[1] = PKFMA(h2(q01.y), w01, acc2[1]);
        acc2[2] = PKFMA(h2(q01.z), w01, acc2[2]);
        acc2[3] = PKFMA(h2(q01.w), w01, acc2[3]);
        acc2[0] = PKFMA(h2(q11.x), w11, acc2[0]);
        acc2[1] = PKFMA(h2(q11.y), w11, acc2[1]);
        acc2[2] = PKFMA(h2(q11.z), w11, acc2[2]);
        acc2[3] = PKFMA(h2(q11.w), w11, acc2[3]);
    }

    // ---- widen to f32, in-block reduction over 4 h-phases, exclusive store
    float acc[BB];
#pragma unroll
    for (int j = 0; j < 4; ++j) {
        acc[2 * j]     = (float)acc2[j].x;
        acc[2 * j + 1] = (float)acc2[j].y;
    }

    __shared__ float part[4][64][BB];        // 8 KB
#pragma unroll
    for (int b = 0; b < BB; b += 4)
        *(float4*)&part[g][lane][b] = make_float4(acc[b], acc[b + 1], acc[b + 2], acc[b + 3]);
    __syncthreads();

    const float sc = 1.0f / 256.0f;
#pragma unroll
    for (int k = 0; k < 2; ++k) {
        const int id = threadIdx.x + k * 256;  // 0..511 -> (b, wl)
        const int b  = id >> 6;
        const int wl = id & 63;
        const float v = part[0][wl][b] + part[1][wl][b] + part[2][wl][b] + part[3][wl][b];
        out[(size_t)b * NA * DD + (size_t)a * DD + wseg * 64 + wl] = v * sc;
    }
}

// ---- fallback (ws too small): direct fp32 gather with atomics -------------
__global__ __launch_bounds__(256) void radon_direct(const float* __restrict__ x,
                                                    float* __restrict__ out) {
    const int a  = blockIdx.x;
    const int hc = blockIdx.y;
    const int w  = threadIdx.x;
    const float ang = (float)a * 0.5f;
    const float t = ang * 0.017453292519943295f;
    const float s = sinf(t);
    const float c = cosf(t);
    const float uw = (float)w - 127.5f;
    const float ax = fmaf(c, uw, 127.5f);
    const float ay = fmaf(s, uw, 127.5f);

    float acc[BB];
#pragma unroll
    for (int b = 0; b < BB; ++b) acc[b] = 0.f;

    const int h0 = hc * 32;
    for (int i = 0; i < 32; ++i) {
        const float uh = (float)(h0 + i) - 127.5f;
        const float ix = fmaf(-s, uh, ax);
        const float iy = fmaf(c, uh, ay);
        const float x0f = floorf(ix), y0f = floorf(iy);
        const float wx1 = ix - x0f, wy1 = iy - y0f;
        const float wx0 = 1.f - wx1, wy0 = 1.f - wy1;
        const int x0 = (int)x0f, y0 = (int)y0f;
        const float vx0 = ((unsigned)x0 < 256u) ? wx0 : 0.f;
        const float vx1 = ((unsigned)(x0 + 1) < 256u) ? wx1 : 0.f;
        const float vy0 = ((unsigned)y0 < 256u) ? wy0 : 0.f;
        const float vy1 = ((unsigned)(y0 + 1) < 256u) ? wy1 : 0.f;
        const int x0c = min(max(x0, 0), 255);
        const int x1c = min(max(x0 + 1, 0), 255);
        const int y0c = min(max(y0, 0), 255);
        const int y1c = min(max(y0 + 1, 0), 255);
        const float w00 = vx0 * vy0, w10 = vx1 * vy0;
        const float w01 = vx0 * vy1, w11 = vx1 * vy1;
        const int l00 = y0c * DD + x0c, l10 = y0c * DD + x1c;
        const int l01 = y1c * DD + x0c, l11 = y1c * DD + x1c;
#pragma unroll
        for (int b = 0; b < BB; ++b) {
            const float* ib = x + (size_t)b * DD * DD;
            acc[b] = fmaf(ib[l00], w00, acc[b]);
            acc[b] = fmaf(ib[l10], w10, acc[b]);
            acc[b] = fmaf(ib[l01], w01, acc[b]);
            acc[b] = fmaf(ib[l11], w11, acc[b]);
        }
    }

    const float sc = 1.0f / 256.0f;
    float* o = out + (size_t)a * DD + w;
#pragma unroll
    for (int b = 0; b < BB; ++b)
        atomicAdd(o + (size_t)b * NA * DD, acc[b] * sc);
}

extern "C" void kernel_launch(void* const* d_in, const int* in_sizes, int n_in,
                              void* d_out, int out_size, void* d_ws, size_t ws_size,
                              hipStream_t stream) {
    const float* x = (const float*)d_in[0];
    float* out = (float*)d_out;

    const size_t need = 2ull * DD * DD * sizeof(uint4);  // 2 MiB
    if (ws_size >= need) {
        uint4* pN = (uint4*)d_ws;
        uint4* pT = pN + (size_t)DD * DD;
        pack_f16<<<256, 256, 0, stream>>>(x, pN, pT);
        radon_pred<<<dim3(NA, 4), 256, 0, stream>>>(pN, pT, out);
    } else {
        (void)hipMemsetAsync(d_out, 0, (size_t)out_size * sizeof(float), stream);
        radon_direct<<<dim3(NA, 8), 256, 0, stream>>>(x, out);
    }
}

// Round 6
// 125.094 us; speedup vs baseline: 2.0487x; 1.0057x over previous
//
#include <hip/hip_runtime.h>

#define DD 256
#define BB 8
#define NA 360

typedef _Float16 half2_t __attribute__((ext_vector_type(2)));

#if defined(__has_builtin)
#if __has_builtin(__builtin_elementwise_fma)
#define PKFMA(a, b, c) __builtin_elementwise_fma((a), (b), (c))
#endif
#endif
#ifndef PKFMA
#define PKFMA(a, b, c) ((a) * (b) + (c))
#endif

__device__ __forceinline__ half2_t h2(unsigned u) {
    return __builtin_bit_cast(half2_t, u);
}
__device__ __forceinline__ half2_t bcast2(float w) {   // v_cvt_pkrtz (w,w)
    return __builtin_bit_cast(half2_t, __builtin_amdgcn_cvt_pkrtz(w, w));
}
__device__ __forceinline__ unsigned pk_f16(float a, float b) {
    unsigned short ua = __builtin_bit_cast(unsigned short, (_Float16)a);
    unsigned short ub = __builtin_bit_cast(unsigned short, (_Float16)b);
    return (unsigned)ua | ((unsigned)ub << 16);
}

// ---- pack: (B,1,D,D) fp32 -> f16x8/pixel pN + transposed pT ---------------
// 256 blocks (16x16 tiles) so pack saturates all 256 CUs (~1.5us).
__global__ __launch_bounds__(256) void pack_f16(const float* __restrict__ x,
                                                uint4* __restrict__ pN,
                                                uint4* __restrict__ pT) {
    __shared__ uint4 t[16][17];
    const int tx = threadIdx.x & 15;
    const int ty = threadIdx.x >> 4;              // 0..15
    const int x0 = (blockIdx.x & 15) * 16;
    const int y0 = (blockIdx.x >> 4) * 16;

    const int pix = (y0 + ty) * DD + x0 + tx;
    uint4 v;
    v.x = pk_f16(x[0 * DD * DD + pix], x[1 * DD * DD + pix]);
    v.y = pk_f16(x[2 * DD * DD + pix], x[3 * DD * DD + pix]);
    v.z = pk_f16(x[4 * DD * DD + pix], x[5 * DD * DD + pix]);
    v.w = pk_f16(x[6 * DD * DD + pix], x[7 * DD * DD + pix]);
    pN[pix] = v;                                   // coalesced
    t[ty][tx] = v;
    __syncthreads();
    // pT[xx*D+yy] = img[yy][xx]
    pT[(x0 + ty) * DD + y0 + tx] = t[tx][ty];      // coalesced
}

// ---- radon (R7/R10 structure — at the scattered-gather address floor) -----
// block = (angle, w-quarter); 4 waves = interleaved h-phases; LDS reduce;
// exclusive coalesced stores (no atomics, no output memset needed).
// Per h-step: 4 scattered b128 loads. Floor model (validated R10 to 0.4%):
// 94.4M gathers / 64 lanes * 32 cyc TA addr-processing / 256 CU / 2.4 GHz
// = 76.8 us. Tested escapes ALL regress or tie:
//   fewer-lines (R2 flat), pair-layout (R5 +27%), 2x TLP (R8 flat),
//   fused barrier (R9 +30%), LDS window (R11 +53%),
//   rolling-quad ~2.2 loads/step (R4-probe 81.6us: sel4 VALU + occupancy
//   loss > load savings), exec-predicated gathers (R5-direct 80.0us:
//   saveexec overhead > clamped-addr calc; TA charge unchanged).
// fp8 rejected: e4m3 ulp at |x|~1 is 0.0625 vs 5.1e-3 budget.
// This structure IS the TA-throughput roofline for this op on gfx950.
__global__ __launch_bounds__(256) void radon_pk(const uint4* __restrict__ pN,
                                                const uint4* __restrict__ pT,
                                                float* __restrict__ out) {
    const int a    = blockIdx.x;            // angle
    const int wseg = blockIdx.y;            // 0..3
    const int g    = threadIdx.x >> 6;      // wave = h-phase 0..3
    const int lane = threadIdx.x & 63;
    const int w    = wseg * 64 + lane;

    const float ang = (float)a * 0.5f;
    const float t = ang * 0.017453292519943295f;
    const float s = sinf(t);
    const float c = cosf(t);

    const float uw  = (float)w - 127.5f;
    const float axN = fmaf(c, uw, 127.5f);
    const float ayN = fmaf(s, uw, 127.5f);

    // inner coord = contiguous dim of chosen layout (h-step = min(|s|,|c|))
    const uint4* __restrict__ P;
    float ax, dx, ay, dy;                    // inner = ax+dx*uh, row = ay+dy*uh
    if (fabsf(s) <= fabsf(c)) { P = pN; ax = axN; dx = -s; ay = ayN; dy = c;  }
    else                      { P = pT; ax = ayN; dx = c;  ay = axN; dy = -s; }

    half2_t acc2[4];
#pragma unroll
    for (int j = 0; j < 4; ++j) acc2[j] = half2_t{(_Float16)0, (_Float16)0};

    // h = g + 4*i : the block's 4 waves march through adjacent h together
#pragma unroll 4
    for (int i = 0; i < 64; ++i) {
        const float uh = (float)(g + 4 * i) - 127.5f;
        const float ix = fmaf(dx, uh, ax);
        const float iy = fmaf(dy, uh, ay);
        const float x0f = floorf(ix), y0f = floorf(iy);
        const float wx1 = ix - x0f, wy1 = iy - y0f;
        const float wx0 = 1.f - wx1, wy0 = 1.f - wy1;
        const int x0 = (int)x0f, y0 = (int)y0f;
        const float vx0 = ((unsigned)x0 < 256u) ? wx0 : 0.f;
        const float vx1 = ((unsigned)(x0 + 1) < 256u) ? wx1 : 0.f;
        const float vy0 = ((unsigned)y0 < 256u) ? wy0 : 0.f;
        const float vy1 = ((unsigned)(y0 + 1) < 256u) ? wy1 : 0.f;
        const int x0c = min(max(x0, 0), 255);
        const int x1c = min(max(x0 + 1, 0), 255);
        const int y0c = min(max(y0, 0), 255);
        const int y1c = min(max(y0 + 1, 0), 255);

        const uint4 q00 = P[y0c * DD + x0c];
        const uint4 q10 = P[y0c * DD + x1c];
        const uint4 q01 = P[y1c * DD + x0c];
        const uint4 q11 = P[y1c * DD + x1c];

        const half2_t w00 = bcast2(vx0 * vy0);
        const half2_t w10 = bcast2(vx1 * vy0);
        const half2_t w01 = bcast2(vx0 * vy1);
        const half2_t w11 = bcast2(vx1 * vy1);

        acc2[0] = PKFMA(h2(q00.x), w00, acc2[0]);
        acc2[1] = PKFMA(h2(q00.y), w00, acc2[1]);
        acc2[2] = PKFMA(h2(q00.z), w00, acc2[2]);
        acc2[3] = PKFMA(h2(q00.w), w00, acc2[3]);
        acc2[0] = PKFMA(h2(q10.x), w10, acc2[0]);
        acc2[1] = PKFMA(h2(q10.y), w10, acc2[1]);
        acc2[2] = PKFMA(h2(q10.z), w10, acc2[2]);
        acc2[3] = PKFMA(h2(q10.w), w10, acc2[3]);
        acc2[0] = PKFMA(h2(q01.x), w01, acc2[0]);
        acc2[1] = PKFMA(h2(q01.y), w01, acc2[1]);
        acc2[2] = PKFMA(h2(q01.z), w01, acc2[2]);
        acc2[3] = PKFMA(h2(q01.w), w01, acc2[3]);
        acc2[0] = PKFMA(h2(q11.x), w11, acc2[0]);
        acc2[1] = PKFMA(h2(q11.y), w11, acc2[1]);
        acc2[2] = PKFMA(h2(q11.z), w11, acc2[2]);
        acc2[3] = PKFMA(h2(q11.w), w11, acc2[3]);
    }

    // ---- widen to f32, in-block reduction over 4 h-phases, exclusive store
    float acc[BB];
#pragma unroll
    for (int j = 0; j < 4; ++j) {
        acc[2 * j]     = (float)acc2[j].x;
        acc[2 * j + 1] = (float)acc2[j].y;
    }

    __shared__ float part[4][64][BB];        // 8 KB
#pragma unroll
    for (int b = 0; b < BB; b += 4)
        *(float4*)&part[g][lane][b] = make_float4(acc[b], acc[b + 1], acc[b + 2], acc[b + 3]);
    __syncthreads();

    const float sc = 1.0f / 256.0f;
#pragma unroll
    for (int k = 0; k < 2; ++k) {
        const int id = threadIdx.x + k * 256;  // 0..511 -> (b, wl)
        const int b  = id >> 6;
        const int wl = id & 63;
        const float v = part[0][wl][b] + part[1][wl][b] + part[2][wl][b] + part[3][wl][b];
        out[(size_t)b * NA * DD + (size_t)a * DD + wseg * 64 + wl] = v * sc;
    }
}

// ---- fallback (ws too small): direct fp32 gather with atomics -------------
__global__ __launch_bounds__(256) void radon_direct(const float* __restrict__ x,
                                                    float* __restrict__ out) {
    const int a  = blockIdx.x;
    const int hc = blockIdx.y;
    const int w  = threadIdx.x;
    const float ang = (float)a * 0.5f;
    const float t = ang * 0.017453292519943295f;
    const float s = sinf(t);
    const float c = cosf(t);
    const float uw = (float)w - 127.5f;
    const float ax = fmaf(c, uw, 127.5f);
    const float ay = fmaf(s, uw, 127.5f);

    float acc[BB];
#pragma unroll
    for (int b = 0; b < BB; ++b) acc[b] = 0.f;

    const int h0 = hc * 32;
    for (int i = 0; i < 32; ++i) {
        const float uh = (float)(h0 + i) - 127.5f;
        const float ix = fmaf(-s, uh, ax);
        const float iy = fmaf(c, uh, ay);
        const float x0f = floorf(ix), y0f = floorf(iy);
        const float wx1 = ix - x0f, wy1 = iy - y0f;
        const float wx0 = 1.f - wx1, wy0 = 1.f - wy1;
        const int x0 = (int)x0f, y0 = (int)y0f;
        const float vx0 = ((unsigned)x0 < 256u) ? wx0 : 0.f;
        const float vx1 = ((unsigned)(x0 + 1) < 256u) ? wx1 : 0.f;
        const float vy0 = ((unsigned)y0 < 256u) ? wy0 : 0.f;
        const float vy1 = ((unsigned)(y0 + 1) < 256u) ? wy1 : 0.f;
        const int x0c = min(max(x0, 0), 255);
        const int x1c = min(max(x0 + 1, 0), 255);
        const int y0c = min(max(y0, 0), 255);
        const int y1c = min(max(y0 + 1, 0), 255);
        const float w00 = vx0 * vy0, w10 = vx1 * vy0;
        const float w01 = vx0 * vy1, w11 = vx1 * vy1;
        const int l00 = y0c * DD + x0c, l10 = y0c * DD + x1c;
        const int l01 = y1c * DD + x0c, l11 = y1c * DD + x1c;
#pragma unroll
        for (int b = 0; b < BB; ++b) {
            const float* ib = x + (size_t)b * DD * DD;
            acc[b] = fmaf(ib[l00], w00, acc[b]);
            acc[b] = fmaf(ib[l10], w10, acc[b]);
            acc[b] = fmaf(ib[l01], w01, acc[b]);
            acc[b] = fmaf(ib[l11], w11, acc[b]);
        }
    }

    const float sc = 1.0f / 256.0f;
    float* o = out + (size_t)a * DD + w;
#pragma unroll
    for (int b = 0; b < BB; ++b)
        atomicAdd(o + (size_t)b * NA * DD, acc[b] * sc);
}

extern "C" void kernel_launch(void* const* d_in, const int* in_sizes, int n_in,
                              void* d_out, int out_size, void* d_ws, size_t ws_size,
                              hipStream_t stream) {
    const float* x = (const float*)d_in[0];
    float* out = (float*)d_out;

    const size_t need = 2ull * DD * DD * sizeof(uint4);  // 2 MiB
    if (ws_size >= need) {
        uint4* pN = (uint4*)d_ws;
        uint4* pT = pN + (size_t)DD * DD;
        pack_f16<<<256, 256, 0, stream>>>(x, pN, pT);
        radon_pk<<<dim3(NA, 4), 256, 0, stream>>>(pN, pT, out);
    } else {
        (void)hipMemsetAsync(d_out, 0, (size_t)out_size * sizeof(float), stream);
        radon_direct<<<dim3(NA, 8), 256, 0, stream>>>(x, out);
    }
}